// Round 10
// baseline (226.149 us; speedup 1.0000x reference)
//
#include <hip/hip_runtime.h>
#include <hip/hip_bf16.h>

#define ALPHA 0.2f
typedef unsigned int uint32;
typedef __attribute__((ext_vector_type(8))) short short8;   // 8 bf16 = 4 VGPRs
typedef __attribute__((ext_vector_type(4))) float f32x4;
typedef __attribute__((ext_vector_type(4))) int i32x4;
typedef __attribute__((ext_vector_type(2))) unsigned int u32x2;

static __device__ __forceinline__ unsigned short f2bf(float f) {
    unsigned int u = __float_as_uint(f);
    u += 0x7fffu + ((u >> 16) & 1u);          // RNE
    return (unsigned short)(u >> 16);
}
static __device__ __forceinline__ uint32 pk2bf(float lo, float hi) {
    return (uint32)f2bf(lo) | ((uint32)f2bf(hi) << 16);
}
static __device__ __forceinline__ float bflo(uint32 u) { return __uint_as_float(u << 16); }
static __device__ __forceinline__ float bfhi(uint32 u) { return __uint_as_float(u & 0xffff0000u); }

// ---------------------------------------------------------------------------
// K1 = hist (blocks 0..nbh-1) ∥ prep (blocks nbh..nbh+24).
// hist: eslot[e] = counts[dst]++ (atomic-return over independent threads,
//       4 edges/thread; NT loads/stores keep the read-once dst/eslot streams
//       out of L2 so counts lines stay resident).
// prep: transpose-cast W -> WBT, Wout -> WoutT (bf16 [n][c]); w1f/w2f = W@a.
// ---------------------------------------------------------------------------
__global__ __launch_bounds__(256) void k1_hist_prep(const int* __restrict__ ei,
                                                    int* __restrict__ counts,
                                                    int* __restrict__ eslot, int E,
                                                    const float* __restrict__ W,
                                                    const float* __restrict__ Wout,
                                                    const float* __restrict__ a1,
                                                    const float* __restrict__ a2,
                                                    unsigned short* __restrict__ WBT,
                                                    unsigned short* __restrict__ WoutT,
                                                    float* __restrict__ w1f,
                                                    float* __restrict__ w2f, int nbh) {
    const int tid = threadIdx.x;
    if ((int)blockIdx.x < nbh) {
        int e0 = (blockIdx.x * 256 + tid) * 4;
        if (e0 + 3 < E) {
            i32x4 d = __builtin_nontemporal_load((const i32x4*)(ei + E + e0));
            int s0 = atomicAdd(&counts[d.x], 1);
            int s1v = atomicAdd(&counts[d.y], 1);
            int s2v = atomicAdd(&counts[d.z], 1);
            int s3 = atomicAdd(&counts[d.w], 1);
            __builtin_nontemporal_store(s0,  eslot + e0);
            __builtin_nontemporal_store(s1v, eslot + e0 + 1);
            __builtin_nontemporal_store(s2v, eslot + e0 + 2);
            __builtin_nontemporal_store(s3,  eslot + e0 + 3);
        } else {
            for (int e = e0; e < E; ++e) eslot[e] = atomicAdd(&counts[ei[E + e]], 1);
        }
        return;
    }
    int bp = blockIdx.x - nbh;
    if (bp < 8) {
        // WBT[n][c] = bf16(W[c][n]) — 16 n-rows per block
        for (int n = bp * 16; n < bp * 16 + 16; ++n)
            for (int c = tid; c < 128; c += 256)
                WBT[n * 128 + c] = f2bf(W[c * 128 + n]);
    } else if (bp < 24) {
        // WoutT[n][c] = bf16(Wout[c][n]), c=0..383 — 8 n-rows per block
        int q = bp - 8;
        for (int n = q * 8; n < q * 8 + 8; ++n)
            for (int c = tid; c < 384; c += 256)
                WoutT[n * 384 + c] = f2bf(Wout[c * 128 + n]);
    } else {
        if (tid < 128) {
            float acc1 = 0.f, acc2 = 0.f;
            for (int c = 0; c < 128; ++c) {
                float w = W[tid * 128 + c];
                acc1 += w * a1[c];
                acc2 += w * a2[c];
            }
            w1f[tid] = acc1;
            w2f[tid] = acc2;
        }
    }
}

// ---------------------------------------------------------------------------
// K2 = mmy (blocks 0..nbm-1) ∥ scan (blocks nbm..).   [round-2 verbatim]
// mmy: 64-row tiles, 16x16x32 bf16 MFMA, Whb = h@W, s1/s2 fused in A-staging.
//   s2 -> PR[n].x; scan -> PR[n].y = rowptr + pristine rowptr[] for agg.
// ---------------------------------------------------------------------------
__global__ __launch_bounds__(256) void k2_mmy_scan(const float* __restrict__ h,
                                                   const unsigned short* __restrict__ WBT,
                                                   const float* __restrict__ w1f,
                                                   const float* __restrict__ w2f,
                                                   unsigned short* __restrict__ Whb,
                                                   float* __restrict__ s1,
                                                   uint2* __restrict__ PR, int M,
                                                   const int* __restrict__ counts,
                                                   int* __restrict__ rowptr,
                                                   int N, int E, int nbm) {
    __shared__ unsigned short As[64 * 128];   // 16KB
    __shared__ unsigned short Bs[128 * 128];  // 32KB (also epilogue transpose buf)
    __shared__ float ws1[128], ws2[128];
    __shared__ int wsums[4];
    __shared__ int base_s;
    const int tid = threadIdx.x;

    if ((int)blockIdx.x >= nbm) {
        // ---------------- scan ----------------
        const int bs   = blockIdx.x - nbm;
        const int lane = tid & 63, wv = tid >> 6;
        const int limit = bs * 1024;
        int acc = 0;
        for (int i = tid * 4; i < limit; i += 1024) {
            int4 v = *(const int4*)(counts + i);
            acc += v.x + v.y + v.z + v.w;
        }
#pragma unroll
        for (int off = 32; off > 0; off >>= 1) acc += __shfl_down(acc, off);
        if (lane == 0) wsums[wv] = acc;
        __syncthreads();
        if (tid == 0) base_s = wsums[0] + wsums[1] + wsums[2] + wsums[3];
        __syncthreads();
        int i0 = bs * 1024 + tid * 4;
        int v0 = 0, v1 = 0, v2 = 0, v3 = 0;
        if (i0 + 3 < N) {
            int4 v = *(const int4*)(counts + i0);
            v0 = v.x; v1 = v.y; v2 = v.z; v3 = v.w;
        } else {
            if (i0 + 0 < N) v0 = counts[i0 + 0];
            if (i0 + 1 < N) v1 = counts[i0 + 1];
            if (i0 + 2 < N) v2 = counts[i0 + 2];
            if (i0 + 3 < N) v3 = counts[i0 + 3];
        }
        int tt = v0 + v1 + v2 + v3;
        int incl = tt;
#pragma unroll
        for (int off = 1; off < 64; off <<= 1) {
            int t = __shfl_up(incl, off);
            if (lane >= off) incl += t;
        }
        __syncthreads();
        if (lane == 63) wsums[wv] = incl;
        __syncthreads();
        int woff = 0;
        for (int w2 = 0; w2 < wv; ++w2) woff += wsums[w2];
        int base = base_s + woff + (incl - tt);
        if (i0 + 0 < N) { rowptr[i0 + 0] = base;                PR[i0 + 0].y = (uint32)base; }
        if (i0 + 1 < N) { rowptr[i0 + 1] = base + v0;           PR[i0 + 1].y = (uint32)(base + v0); }
        if (i0 + 2 < N) { rowptr[i0 + 2] = base + v0 + v1;      PR[i0 + 2].y = (uint32)(base + v0 + v1); }
        if (i0 + 3 < N) { rowptr[i0 + 3] = base + v0 + v1 + v2; PR[i0 + 3].y = (uint32)(base + v0 + v1 + v2); }
        if (bs == 0 && tid == 0) rowptr[N] = E;
        return;
    }

    // ---------------- mmy (64-row tile) ----------------
    const int lane = tid & 63;
    const int w    = tid >> 6;
    const int row0 = blockIdx.x * 64;

    if (tid < 128) ws1[tid] = w1f[tid];
    else           ws2[tid - 128] = w2f[tid - 128];
    __syncthreads();

    // stage A (fp32 -> bf16) + fused fp32 score partials
    const float4* h4 = (const float4*)h;
    float sp1[4], sp2[4];
#pragma unroll
    for (int m = 0; m < 4; ++m) { sp1[m] = 0.f; sp2[m] = 0.f; }
#pragma unroll
    for (int m = 0; m < 4; ++m) {
        int i = m * 256 + tid;            // 0..1023
        int r = i >> 4, g = i & 15;
        int rg = row0 + r;
        float4 va = make_float4(0.f, 0.f, 0.f, 0.f), vb = va;
        if (rg < M) {
            va = h4[(size_t)rg * 32 + g * 2];
            vb = h4[(size_t)rg * 32 + g * 2 + 1];
        }
        float4 wa1 = *(const float4*)(ws1 + g * 8);
        float4 wb1 = *(const float4*)(ws1 + g * 8 + 4);
        float4 wa2 = *(const float4*)(ws2 + g * 8);
        float4 wb2 = *(const float4*)(ws2 + g * 8 + 4);
        sp1[m] += va.x * wa1.x + va.y * wa1.y + va.z * wa1.z + va.w * wa1.w
                + vb.x * wb1.x + vb.y * wb1.y + vb.z * wb1.z + vb.w * wb1.w;
        sp2[m] += va.x * wa2.x + va.y * wa2.y + va.z * wa2.z + va.w * wa2.w
                + vb.x * wb2.x + vb.y * wb2.y + vb.z * wb2.z + vb.w * wb2.w;
        uint4 u;
        u.x = pk2bf(va.x, va.y); u.y = pk2bf(va.z, va.w);
        u.z = pk2bf(vb.x, vb.y); u.w = pk2bf(vb.z, vb.w);
        *(uint4*)(As + r * 128 + ((g ^ (r & 15)) * 8)) = u;
    }
#pragma unroll
    for (int m = 0; m < 4; ++m) {
#pragma unroll
        for (int off = 1; off < 16; off <<= 1) {
            sp1[m] += __shfl_xor(sp1[m], off);
            sp2[m] += __shfl_xor(sp2[m], off);
        }
    }
    if ((tid & 15) == 0) {
#pragma unroll
        for (int m = 0; m < 4; ++m) {
            int rg = row0 + m * 16 + (tid >> 4);
            if (rg < M) { s1[rg] = sp1[m]; PR[rg].x = __float_as_uint(sp2[m]); }
        }
    }

    // stage B = WBT (128 n-rows, 128 k)
#pragma unroll
    for (int m = 0; m < 8; ++m) {
        int i = m * 256 + tid;
        int n = i >> 4, g = i & 15;
        uint4 v = *(const uint4*)(WBT + n * 128 + g * 8);
        *(uint4*)(Bs + n * 128 + ((g ^ (n & 15)) * 8)) = v;
    }
    __syncthreads();

    const int ml   = lane & 15;
    const int quad = lane >> 4;
    f32x4 acc[8];
#pragma unroll
    for (int nt = 0; nt < 8; ++nt) acc[nt] = (f32x4){0.f, 0.f, 0.f, 0.f};
#pragma unroll
    for (int kc = 0; kc < 4; ++kc) {
        int gl = ((kc * 4 + quad) ^ ml) * 8;
        short8 af = *(const short8*)(As + (w * 16 + ml) * 128 + gl);
#pragma unroll
        for (int nt = 0; nt < 8; ++nt) {
            short8 bf = *(const short8*)(Bs + (nt * 16 + ml) * 128 + gl);
            acc[nt] = __builtin_amdgcn_mfma_f32_16x16x32_bf16(af, bf, acc[nt], 0, 0, 0);
        }
    }
    // epilogue: acc -> Ct (=Bs, free now) -> coalesced uint4 stores of Whb
    __syncthreads();                  // all waves done reading As/Bs
    unsigned short* Ct = Bs;          // stride 136 shorts (272B, 16B-aligned)
    int lrow = w * 16 + quad * 4;
#pragma unroll
    for (int r = 0; r < 4; ++r)
#pragma unroll
        for (int nt = 0; nt < 8; ++nt)
            Ct[(lrow + r) * 136 + nt * 16 + ml] = f2bf(acc[nt][r]);
    __syncthreads();
#pragma unroll
    for (int m = 0; m < 4; ++m) {
        int i = m * 256 + tid;        // 0..1023
        int r2 = i >> 4, g = i & 15;
        int rg = row0 + r2;
        uint4 v = *(const uint4*)(Ct + r2 * 136 + g * 8);
        if (rg < M)
            *(uint4*)(Whb + (size_t)rg * 128 + g * 8) = v;
    }
}

// ---------------------------------------------------------------------------
// scatter: 4 edges/thread. NT loads for the read-once ei/ef/eslot streams and
// NT stores for the random rec8 records — keeps per-XCD L2 reserved for the
// s1/PR gather tables (and leaves Whb warm for the following agg).
// pos = PR[dst].y + eslot[e]; 8B record {src:17b | ex0..ex2:15b}.
// ---------------------------------------------------------------------------
__global__ __launch_bounds__(256) void scatter_kernel(const int* __restrict__ ei,
                                                      const float* __restrict__ ef,
                                                      const float* __restrict__ s1,
                                                      const uint2* __restrict__ PR,
                                                      const int* __restrict__ eslot,
                                                      uint2* __restrict__ rec8, int E) {
    int e0 = (blockIdx.x * blockDim.x + threadIdx.x) * 4;
    if (e0 >= E) return;
    if (e0 + 3 < E) {
        i32x4 sv = __builtin_nontemporal_load((const i32x4*)(ei + e0));
        i32x4 dv = __builtin_nontemporal_load((const i32x4*)(ei + E + e0));
        i32x4 es = __builtin_nontemporal_load((const i32x4*)(eslot + e0));
        f32x4 f0 = __builtin_nontemporal_load((const f32x4*)(ef + (size_t)e0 * 3));
        f32x4 f1 = __builtin_nontemporal_load((const f32x4*)(ef + (size_t)e0 * 3 + 4));
        f32x4 f2 = __builtin_nontemporal_load((const f32x4*)(ef + (size_t)e0 * 3 + 8));
        float sa = s1[sv.x], sb = s1[sv.y], sc = s1[sv.z], sd = s1[sv.w];
        uint2 pa = PR[dv.x], pb = PR[dv.y], pc = PR[dv.z], pd = PR[dv.w];
        float s_a = sa + __uint_as_float(pa.x);
        float s_b = sb + __uint_as_float(pb.x);
        float s_c = sc + __uint_as_float(pc.x);
        float s_d = sd + __uint_as_float(pd.x);
        s_a = (s_a >= 0.f) ? s_a : ALPHA * s_a;
        s_b = (s_b >= 0.f) ? s_b : ALPHA * s_b;
        s_c = (s_c >= 0.f) ? s_c : ALPHA * s_c;
        s_d = (s_d >= 0.f) ? s_d : ALPHA * s_d;
        u32x2 rv;
        rv.x = (uint32)sv.x | ((uint32)(f2bf(__expf(s_a * f0.x)) & 0x7fffu) << 17);
        rv.y = (uint32)(f2bf(__expf(s_a * f0.y)) & 0x7fffu)
             | ((uint32)(f2bf(__expf(s_a * f0.z)) & 0x7fffu) << 15);
        __builtin_nontemporal_store(rv, (u32x2*)(rec8 + (int)pa.y + es.x));
        rv.x = (uint32)sv.y | ((uint32)(f2bf(__expf(s_b * f0.w)) & 0x7fffu) << 17);
        rv.y = (uint32)(f2bf(__expf(s_b * f1.x)) & 0x7fffu)
             | ((uint32)(f2bf(__expf(s_b * f1.y)) & 0x7fffu) << 15);
        __builtin_nontemporal_store(rv, (u32x2*)(rec8 + (int)pb.y + es.y));
        rv.x = (uint32)sv.z | ((uint32)(f2bf(__expf(s_c * f1.z)) & 0x7fffu) << 17);
        rv.y = (uint32)(f2bf(__expf(s_c * f1.w)) & 0x7fffu)
             | ((uint32)(f2bf(__expf(s_c * f2.x)) & 0x7fffu) << 15);
        __builtin_nontemporal_store(rv, (u32x2*)(rec8 + (int)pc.y + es.z));
        rv.x = (uint32)sv.w | ((uint32)(f2bf(__expf(s_d * f2.y)) & 0x7fffu) << 17);
        rv.y = (uint32)(f2bf(__expf(s_d * f2.z)) & 0x7fffu)
             | ((uint32)(f2bf(__expf(s_d * f2.w)) & 0x7fffu) << 15);
        __builtin_nontemporal_store(rv, (u32x2*)(rec8 + (int)pd.y + es.w));
    } else {
        for (int e = e0; e < E; ++e) {
            int src = ei[e];
            int dst = ei[E + e];
            uint2 pr = PR[dst];
            float s = s1[src] + __uint_as_float(pr.x);
            s = (s >= 0.f) ? s : ALPHA * s;
            unsigned short b0 = f2bf(__expf(s * ef[(size_t)e * 3 + 0]));
            unsigned short b1 = f2bf(__expf(s * ef[(size_t)e * 3 + 1]));
            unsigned short b2 = f2bf(__expf(s * ef[(size_t)e * 3 + 2]));
            uint2 rv;
            rv.x = (uint32)src | ((uint32)(b0 & 0x7fffu) << 17);
            rv.y = (uint32)(b1 & 0x7fffu) | ((uint32)(b2 & 0x7fffu) << 15);
            rec8[(int)pr.y + eslot[e]] = rv;
        }
    }
}

// ---------------------------------------------------------------------------
// agg: one wave per node, atomic-free, one pass, SCALARIZED + software-
// pipelined (next x8 batch's rec8 s_loads issued under current Yu gathers).
// Weight decode on SALU; FMAs take SGPR weight directly.
// [r3/r6 lessons: no cursor atomics, no LDS flush, no inter-wave barrier]
// ---------------------------------------------------------------------------
__global__ __launch_bounds__(256) void agg_kernel(const uint2* __restrict__ rec8,
                                                  const int* __restrict__ rowptr,
                                                  const uint32* __restrict__ Yu,
                                                  uint32* __restrict__ zo, int N) {
    int node = (blockIdx.x * blockDim.x + threadIdx.x) >> 6;
    int lane = threadIdx.x & 63;
    if (node >= N) return;
    int nu  = __builtin_amdgcn_readfirstlane(node);
    int beg = rowptr[nu], end = rowptr[nu + 1];

    float d0 = 0.f, d1 = 0.f, d2 = 0.f;
    float z0l = 0.f, z0h = 0.f, z1l = 0.f, z1h = 0.f, z2l = 0.f, z2h = 0.f;
    int j = beg;

    uint2 rr[8];
    if (j + 7 < end) {
        const uint2* rb = rec8 + (unsigned)__builtin_amdgcn_readfirstlane(j);
#pragma unroll
        for (int q = 0; q < 8; ++q) rr[q] = rb[q];
    }
    while (j + 7 < end) {
        uint32 sx[8], sy[8];
#pragma unroll
        for (int q = 0; q < 8; ++q) {
            sx[q] = __builtin_amdgcn_readfirstlane(rr[q].x);
            sy[q] = __builtin_amdgcn_readfirstlane(rr[q].y);
        }
        uint32 u[8];
#pragma unroll
        for (int q = 0; q < 8; ++q)
            u[q] = Yu[(size_t)(sx[q] & 0x1ffffu) * 64 + lane];
        int jn = j + 8;
        if (jn + 7 < end) {                       // prefetch next batch (SGPR)
            const uint2* rb = rec8 + (unsigned)__builtin_amdgcn_readfirstlane(jn);
#pragma unroll
            for (int q = 0; q < 8; ++q) rr[q] = rb[q];
        }
#pragma unroll
        for (int q = 0; q < 8; ++q) {
            float w0 = __uint_as_float((sx[q] >> 1) & 0x7fff0000u);
            float w1 = __uint_as_float((sy[q] << 16) & 0x7fff0000u);
            float w2 = __uint_as_float((sy[q] << 1) & 0x7fff0000u);
            d0 += w0; d1 += w1; d2 += w2;
            float yl = bflo(u[q]), yh = bfhi(u[q]);
            z0l += w0 * yl; z0h += w0 * yh;
            z1l += w1 * yl; z1h += w1 * yh;
            z2l += w2 * yl; z2h += w2 * yh;
        }
        j = jn;
    }
    for (; j + 3 < end; j += 4) {
        const uint2* rb = rec8 + (unsigned)__builtin_amdgcn_readfirstlane(j);
        uint2 r4[4];
#pragma unroll
        for (int q = 0; q < 4; ++q) r4[q] = rb[q];
        uint32 sx[4], sy[4];
#pragma unroll
        for (int q = 0; q < 4; ++q) {
            sx[q] = __builtin_amdgcn_readfirstlane(r4[q].x);
            sy[q] = __builtin_amdgcn_readfirstlane(r4[q].y);
        }
        uint32 u[4];
#pragma unroll
        for (int q = 0; q < 4; ++q)
            u[q] = Yu[(size_t)(sx[q] & 0x1ffffu) * 64 + lane];
#pragma unroll
        for (int q = 0; q < 4; ++q) {
            float w0 = __uint_as_float((sx[q] >> 1) & 0x7fff0000u);
            float w1 = __uint_as_float((sy[q] << 16) & 0x7fff0000u);
            float w2 = __uint_as_float((sy[q] << 1) & 0x7fff0000u);
            d0 += w0; d1 += w1; d2 += w2;
            float yl = bflo(u[q]), yh = bfhi(u[q]);
            z0l += w0 * yl; z0h += w0 * yh;
            z1l += w1 * yl; z1h += w1 * yh;
            z2l += w2 * yl; z2h += w2 * yh;
        }
    }
    for (; j < end; ++j) {
        const uint2* rb = rec8 + (unsigned)__builtin_amdgcn_readfirstlane(j);
        uint2 r0 = rb[0];
        uint32 sx = __builtin_amdgcn_readfirstlane(r0.x);
        uint32 sy = __builtin_amdgcn_readfirstlane(r0.y);
        uint32 u0 = Yu[(size_t)(sx & 0x1ffffu) * 64 + lane];
        float w0 = __uint_as_float((sx >> 1) & 0x7fff0000u);
        float w1 = __uint_as_float((sy << 16) & 0x7fff0000u);
        float w2 = __uint_as_float((sy << 1) & 0x7fff0000u);
        d0 += w0; d1 += w1; d2 += w2;
        float yl = bflo(u0), yh = bfhi(u0);
        z0l += w0 * yl; z0h += w0 * yh;
        z1l += w1 * yl; z1h += w1 * yh;
        z2l += w2 * yl; z2h += w2 * yh;
    }
    float i0 = 1.f / (d0 + 1e-16f);
    float i1 = 1.f / (d1 + 1e-16f);
    float i2 = 1.f / (d2 + 1e-16f);
    size_t zb = (size_t)node * 192;
    zo[zb + lane]       = pk2bf(z0l * i0, z0h * i0);
    zo[zb + 64 + lane]  = pk2bf(z1l * i1, z1h * i1);
    zo[zb + 128 + lane] = pk2bf(z2l * i2, z2h * i2);
}

// ---------------------------------------------------------------------------
// K5: out[N,128] = z[N,384] @ Wout[384,128].   [round-2 verbatim]
// ---------------------------------------------------------------------------
__global__ __launch_bounds__(256) void k5_gemm(const unsigned short* __restrict__ z,
                                               const unsigned short* __restrict__ WoutT,
                                               float* __restrict__ out, int M) {
    __shared__ __align__(16) char smem[49152];
    unsigned short* As = (unsigned short*)smem;            // 64*128 bf16 = 16KB
    unsigned short* Bs = (unsigned short*)(smem + 16384);  // 128*128 bf16 = 32KB
    float* Ct = (float*)smem;                              // 64*132 f32 (epilogue)
    const int tid = threadIdx.x;
    const int lane = tid & 63, w = tid >> 6;
    const int ml = lane & 15, quad = lane >> 4;
    const int row0 = blockIdx.x * 64;

    f32x4 acc[8];
#pragma unroll
    for (int nt = 0; nt < 8; ++nt) acc[nt] = (f32x4){0.f, 0.f, 0.f, 0.f};

    for (int ks = 0; ks < 3; ++ks) {
        __syncthreads();              // prev slice compute done
#pragma unroll
        for (int m = 0; m < 4; ++m) { // stage A slice: 64 rows x 128 bf16
            int i = m * 256 + tid;
            int r = i >> 4, g = i & 15;
            int rg = row0 + r;
            uint4 v = make_uint4(0u, 0u, 0u, 0u);
            if (rg < M) v = *(const uint4*)(z + (size_t)rg * 384 + ks * 128 + g * 8);
            *(uint4*)(As + r * 128 + ((g ^ (r & 15)) * 8)) = v;
        }
#pragma unroll
        for (int m = 0; m < 8; ++m) { // stage B slice: 128 n-rows x 128 k
            int i = m * 256 + tid;
            int n = i >> 4, g = i & 15;
            uint4 v = *(const uint4*)(WoutT + n * 384 + ks * 128 + g * 8);
            *(uint4*)(Bs + n * 128 + ((g ^ (n & 15)) * 8)) = v;
        }
        __syncthreads();
#pragma unroll
        for (int kc = 0; kc < 4; ++kc) {
            int gl = ((kc * 4 + quad) ^ ml) * 8;
            short8 af = *(const short8*)(As + (w * 16 + ml) * 128 + gl);
#pragma unroll
            for (int nt = 0; nt < 8; ++nt) {
                short8 bf = *(const short8*)(Bs + (nt * 16 + ml) * 128 + gl);
                acc[nt] = __builtin_amdgcn_mfma_f32_16x16x32_bf16(af, bf, acc[nt], 0, 0, 0);
            }
        }
    }
    __syncthreads();
    int lrow = w * 16 + quad * 4;
#pragma unroll
    for (int r = 0; r < 4; ++r)
#pragma unroll
        for (int nt = 0; nt < 8; ++nt)
            Ct[(lrow + r) * 132 + nt * 16 + ml] = acc[nt][r];
    __syncthreads();
#pragma unroll
    for (int m = 0; m < 8; ++m) {
        int i = m * 256 + tid;
        int r2 = i >> 5, g = i & 31;
        int rg = row0 + r2;
        if (rg < M)
            *(float4*)(out + (size_t)rg * 128 + g * 4) = *(const float4*)(Ct + r2 * 132 + g * 4);
    }
}

// ---------------------------------------------------------------------------
extern "C" void kernel_launch(void* const* d_in, const int* in_sizes, int n_in,
                              void* d_out, int out_size, void* d_ws, size_t ws_size,
                              hipStream_t stream) {
    const float* h    = (const float*)d_in[0];
    const int*   ei   = (const int*)d_in[1];    // [2, E]
    const float* ef   = (const float*)d_in[2];  // [E, 3]
    const float* W    = (const float*)d_in[3];  // [128,128]
    const float* a1   = (const float*)d_in[4];  // [128]
    const float* a2   = (const float*)d_in[5];  // [128]
    const float* Wout = (const float*)d_in[6];  // [384,128]
    float*       out  = (float*)d_out;

    const int N = in_sizes[0] / 128;  // 50000
    const int E = in_sizes[2] / 3;    // 800000
    const int nchunk = (N + 1023) / 1024;
    const int nbh    = (E + 1023) / 1024;  // hist blocks (4 edges/thread)
    const int nbm    = (N + 63) / 64;      // mmy blocks

    // workspace layout (rec8 first -> 16B alignment for everything vectorized)
    uint2* rec8 = (uint2*)d_ws;                           // E * 8B
    unsigned short* Whb = (unsigned short*)(rec8 + E);    // N*128 bf16 (12.8MB)
    unsigned short* WBT = Whb + (size_t)N * 128;          // 128*128 bf16
    unsigned short* WoutT = WBT + 128 * 128;              // 128*384 bf16
    float* w1f  = (float*)(WoutT + 128 * 384);            // 128
    float* w2f  = w1f + 128;                              // 128
    float* s1   = w2f + 128;                              // N
    uint2* PR   = (uint2*)(s1 + N);                       // N pairs {s2, rowptr}
    int* rowptr = (int*)(PR + N);                         // N+4 (16B-align pad)
    unsigned short* zbuf = (unsigned short*)(rowptr + N + 4);  // N*384 bf16 (38.4MB)
    // counts/eslot alias zbuf: dead before agg writes z (stream order)
    int* counts = (int*)zbuf;                             // N
    int* eslot  = counts + N;                             // E

    (void)hipMemsetAsync(counts, 0, (size_t)N * sizeof(int), stream);

    k1_hist_prep<<<nbh + 25, 256, 0, stream>>>(ei, counts, eslot, E,
                                               W, Wout, a1, a2, WBT, WoutT, w1f, w2f, nbh);
    k2_mmy_scan<<<nbm + nchunk, 256, 0, stream>>>(h, WBT, w1f, w2f, Whb, s1, PR, N,
                                                  counts, rowptr, N, E, nbm);
    scatter_kernel<<<(E / 4 + 255) / 256, 256, 0, stream>>>(ei, ef, s1, PR, eslot, rec8, E);
    agg_kernel<<<(N * 64 + 255) / 256, 256, 0, stream>>>(rec8, rowptr, (const uint32*)Whb,
                                                         (uint32*)zbuf, N);
    k5_gemm<<<(N + 63) / 64, 256, 0, stream>>>(zbuf, WoutT, out, N);
}

// Round 11
// 213.138 us; speedup vs baseline: 1.0610x; 1.0610x over previous
//
#include <hip/hip_runtime.h>
#include <hip/hip_bf16.h>

#define ALPHA 0.2f
typedef unsigned int uint32;
typedef __attribute__((ext_vector_type(8))) short short8;   // 8 bf16 = 4 VGPRs
typedef __attribute__((ext_vector_type(4))) float f32x4;

static __device__ __forceinline__ unsigned short f2bf(float f) {
    unsigned int u = __float_as_uint(f);
    u += 0x7fffu + ((u >> 16) & 1u);          // RNE
    return (unsigned short)(u >> 16);
}
static __device__ __forceinline__ uint32 pk2bf(float lo, float hi) {
    return (uint32)f2bf(lo) | ((uint32)f2bf(hi) << 16);
}
static __device__ __forceinline__ float bflo(uint32 u) { return __uint_as_float(u << 16); }
static __device__ __forceinline__ float bfhi(uint32 u) { return __uint_as_float(u & 0xffff0000u); }

// ---------------------------------------------------------------------------
// K1 = hist (blocks 0..nbh-1) ∥ prep (blocks nbh..nbh+24).
// hist: eslot[e] = counts[dst]++ (atomic-return over independent threads,
//       4 edges/thread int4. Round-3: cursor atomics in scatter serialize.
//       Round-6: LDS-CAS flush serializes. Round-10: NT stores on eslot/rec8
//       kill producer->consumer L2 forwarding (-13us). This is the optimum.)
// prep: transpose-cast W -> WBT, Wout -> WoutT (bf16 [n][c]); w1f/w2f = W@a.
// ---------------------------------------------------------------------------
__global__ __launch_bounds__(256) void k1_hist_prep(const int* __restrict__ ei,
                                                    int* __restrict__ counts,
                                                    int* __restrict__ eslot, int E,
                                                    const float* __restrict__ W,
                                                    const float* __restrict__ Wout,
                                                    const float* __restrict__ a1,
                                                    const float* __restrict__ a2,
                                                    unsigned short* __restrict__ WBT,
                                                    unsigned short* __restrict__ WoutT,
                                                    float* __restrict__ w1f,
                                                    float* __restrict__ w2f, int nbh) {
    const int tid = threadIdx.x;
    if ((int)blockIdx.x < nbh) {
        int e0 = (blockIdx.x * 256 + tid) * 4;
        if (e0 + 3 < E) {
            int4 d = *(const int4*)(ei + E + e0);
            int s0 = atomicAdd(&counts[d.x], 1);
            int s1v = atomicAdd(&counts[d.y], 1);
            int s2v = atomicAdd(&counts[d.z], 1);
            int s3 = atomicAdd(&counts[d.w], 1);
            eslot[e0]     = s0;
            eslot[e0 + 1] = s1v;
            eslot[e0 + 2] = s2v;
            eslot[e0 + 3] = s3;
        } else {
            for (int e = e0; e < E; ++e) eslot[e] = atomicAdd(&counts[ei[E + e]], 1);
        }
        return;
    }
    int bp = blockIdx.x - nbh;
    if (bp < 8) {
        // WBT[n][c] = bf16(W[c][n]) — 16 n-rows per block
        for (int n = bp * 16; n < bp * 16 + 16; ++n)
            for (int c = tid; c < 128; c += 256)
                WBT[n * 128 + c] = f2bf(W[c * 128 + n]);
    } else if (bp < 24) {
        // WoutT[n][c] = bf16(Wout[c][n]), c=0..383 — 8 n-rows per block
        int q = bp - 8;
        for (int n = q * 8; n < q * 8 + 8; ++n)
            for (int c = tid; c < 384; c += 256)
                WoutT[n * 384 + c] = f2bf(Wout[c * 128 + n]);
    } else {
        if (tid < 128) {
            float acc1 = 0.f, acc2 = 0.f;
            for (int c = 0; c < 128; ++c) {
                float w = W[tid * 128 + c];
                acc1 += w * a1[c];
                acc2 += w * a2[c];
            }
            w1f[tid] = acc1;
            w2f[tid] = acc2;
        }
    }
}

// ---------------------------------------------------------------------------
// K2 = mmy (blocks 0..nbm-1) ∥ scan (blocks nbm..).   [round-2 verbatim]
// mmy: 64-row tiles, 16x16x32 bf16 MFMA, Whb = h@W, s1/s2 fused in A-staging.
//   s2 -> PR[n].x; scan -> PR[n].y = rowptr + pristine rowptr[] for agg.
// ---------------------------------------------------------------------------
__global__ __launch_bounds__(256) void k2_mmy_scan(const float* __restrict__ h,
                                                   const unsigned short* __restrict__ WBT,
                                                   const float* __restrict__ w1f,
                                                   const float* __restrict__ w2f,
                                                   unsigned short* __restrict__ Whb,
                                                   float* __restrict__ s1,
                                                   uint2* __restrict__ PR, int M,
                                                   const int* __restrict__ counts,
                                                   int* __restrict__ rowptr,
                                                   int N, int E, int nbm) {
    __shared__ unsigned short As[64 * 128];   // 16KB
    __shared__ unsigned short Bs[128 * 128];  // 32KB (also epilogue transpose buf)
    __shared__ float ws1[128], ws2[128];
    __shared__ int wsums[4];
    __shared__ int base_s;
    const int tid = threadIdx.x;

    if ((int)blockIdx.x >= nbm) {
        // ---------------- scan ----------------
        const int bs   = blockIdx.x - nbm;
        const int lane = tid & 63, wv = tid >> 6;
        const int limit = bs * 1024;
        int acc = 0;
        for (int i = tid * 4; i < limit; i += 1024) {
            int4 v = *(const int4*)(counts + i);
            acc += v.x + v.y + v.z + v.w;
        }
#pragma unroll
        for (int off = 32; off > 0; off >>= 1) acc += __shfl_down(acc, off);
        if (lane == 0) wsums[wv] = acc;
        __syncthreads();
        if (tid == 0) base_s = wsums[0] + wsums[1] + wsums[2] + wsums[3];
        __syncthreads();
        int i0 = bs * 1024 + tid * 4;
        int v0 = 0, v1 = 0, v2 = 0, v3 = 0;
        if (i0 + 3 < N) {
            int4 v = *(const int4*)(counts + i0);
            v0 = v.x; v1 = v.y; v2 = v.z; v3 = v.w;
        } else {
            if (i0 + 0 < N) v0 = counts[i0 + 0];
            if (i0 + 1 < N) v1 = counts[i0 + 1];
            if (i0 + 2 < N) v2 = counts[i0 + 2];
            if (i0 + 3 < N) v3 = counts[i0 + 3];
        }
        int tt = v0 + v1 + v2 + v3;
        int incl = tt;
#pragma unroll
        for (int off = 1; off < 64; off <<= 1) {
            int t = __shfl_up(incl, off);
            if (lane >= off) incl += t;
        }
        __syncthreads();
        if (lane == 63) wsums[wv] = incl;
        __syncthreads();
        int woff = 0;
        for (int w2 = 0; w2 < wv; ++w2) woff += wsums[w2];
        int base = base_s + woff + (incl - tt);
        if (i0 + 0 < N) { rowptr[i0 + 0] = base;                PR[i0 + 0].y = (uint32)base; }
        if (i0 + 1 < N) { rowptr[i0 + 1] = base + v0;           PR[i0 + 1].y = (uint32)(base + v0); }
        if (i0 + 2 < N) { rowptr[i0 + 2] = base + v0 + v1;      PR[i0 + 2].y = (uint32)(base + v0 + v1); }
        if (i0 + 3 < N) { rowptr[i0 + 3] = base + v0 + v1 + v2; PR[i0 + 3].y = (uint32)(base + v0 + v1 + v2); }
        if (bs == 0 && tid == 0) rowptr[N] = E;
        return;
    }

    // ---------------- mmy (64-row tile) ----------------
    const int lane = tid & 63;
    const int w    = tid >> 6;
    const int row0 = blockIdx.x * 64;

    if (tid < 128) ws1[tid] = w1f[tid];
    else           ws2[tid - 128] = w2f[tid - 128];
    __syncthreads();

    // stage A (fp32 -> bf16) + fused fp32 score partials
    const float4* h4 = (const float4*)h;
    float sp1[4], sp2[4];
#pragma unroll
    for (int m = 0; m < 4; ++m) { sp1[m] = 0.f; sp2[m] = 0.f; }
#pragma unroll
    for (int m = 0; m < 4; ++m) {
        int i = m * 256 + tid;            // 0..1023
        int r = i >> 4, g = i & 15;
        int rg = row0 + r;
        float4 va = make_float4(0.f, 0.f, 0.f, 0.f), vb = va;
        if (rg < M) {
            va = h4[(size_t)rg * 32 + g * 2];
            vb = h4[(size_t)rg * 32 + g * 2 + 1];
        }
        float4 wa1 = *(const float4*)(ws1 + g * 8);
        float4 wb1 = *(const float4*)(ws1 + g * 8 + 4);
        float4 wa2 = *(const float4*)(ws2 + g * 8);
        float4 wb2 = *(const float4*)(ws2 + g * 8 + 4);
        sp1[m] += va.x * wa1.x + va.y * wa1.y + va.z * wa1.z + va.w * wa1.w
                + vb.x * wb1.x + vb.y * wb1.y + vb.z * wb1.z + vb.w * wb1.w;
        sp2[m] += va.x * wa2.x + va.y * wa2.y + va.z * wa2.z + va.w * wa2.w
                + vb.x * wb2.x + vb.y * wb2.y + vb.z * wb2.z + vb.w * wb2.w;
        uint4 u;
        u.x = pk2bf(va.x, va.y); u.y = pk2bf(va.z, va.w);
        u.z = pk2bf(vb.x, vb.y); u.w = pk2bf(vb.z, vb.w);
        *(uint4*)(As + r * 128 + ((g ^ (r & 15)) * 8)) = u;
    }
#pragma unroll
    for (int m = 0; m < 4; ++m) {
#pragma unroll
        for (int off = 1; off < 16; off <<= 1) {
            sp1[m] += __shfl_xor(sp1[m], off);
            sp2[m] += __shfl_xor(sp2[m], off);
        }
    }
    if ((tid & 15) == 0) {
#pragma unroll
        for (int m = 0; m < 4; ++m) {
            int rg = row0 + m * 16 + (tid >> 4);
            if (rg < M) { s1[rg] = sp1[m]; PR[rg].x = __float_as_uint(sp2[m]); }
        }
    }

    // stage B = WBT (128 n-rows, 128 k)
#pragma unroll
    for (int m = 0; m < 8; ++m) {
        int i = m * 256 + tid;
        int n = i >> 4, g = i & 15;
        uint4 v = *(const uint4*)(WBT + n * 128 + g * 8);
        *(uint4*)(Bs + n * 128 + ((g ^ (n & 15)) * 8)) = v;
    }
    __syncthreads();

    const int ml   = lane & 15;
    const int quad = lane >> 4;
    f32x4 acc[8];
#pragma unroll
    for (int nt = 0; nt < 8; ++nt) acc[nt] = (f32x4){0.f, 0.f, 0.f, 0.f};
#pragma unroll
    for (int kc = 0; kc < 4; ++kc) {
        int gl = ((kc * 4 + quad) ^ ml) * 8;
        short8 af = *(const short8*)(As + (w * 16 + ml) * 128 + gl);
#pragma unroll
        for (int nt = 0; nt < 8; ++nt) {
            short8 bf = *(const short8*)(Bs + (nt * 16 + ml) * 128 + gl);
            acc[nt] = __builtin_amdgcn_mfma_f32_16x16x32_bf16(af, bf, acc[nt], 0, 0, 0);
        }
    }
    // epilogue: acc -> Ct (=Bs, free now) -> coalesced uint4 stores of Whb
    __syncthreads();                  // all waves done reading As/Bs
    unsigned short* Ct = Bs;          // stride 136 shorts (272B, 16B-aligned)
    int lrow = w * 16 + quad * 4;
#pragma unroll
    for (int r = 0; r < 4; ++r)
#pragma unroll
        for (int nt = 0; nt < 8; ++nt)
            Ct[(lrow + r) * 136 + nt * 16 + ml] = f2bf(acc[nt][r]);
    __syncthreads();
#pragma unroll
    for (int m = 0; m < 4; ++m) {
        int i = m * 256 + tid;        // 0..1023
        int r2 = i >> 4, g = i & 15;
        int rg = row0 + r2;
        uint4 v = *(const uint4*)(Ct + r2 * 136 + g * 8);
        if (rg < M)
            *(uint4*)(Whb + (size_t)rg * 128 + g * 8) = v;
    }
}

// ---------------------------------------------------------------------------
// scatter: 4 edges/thread, vectorized int4/float4 streams -> 4 independent
// gather chains (s1, PR) per thread. pos = PR[dst].y + eslot[e]; 8B record
// {src:17b | ex0:15b, ex1:15b | ex2:15b<<15}.
// ---------------------------------------------------------------------------
__global__ __launch_bounds__(256) void scatter_kernel(const int* __restrict__ ei,
                                                      const float* __restrict__ ef,
                                                      const float* __restrict__ s1,
                                                      const uint2* __restrict__ PR,
                                                      const int* __restrict__ eslot,
                                                      uint2* __restrict__ rec8, int E) {
    int e0 = (blockIdx.x * blockDim.x + threadIdx.x) * 4;
    if (e0 >= E) return;
    if (e0 + 3 < E) {
        int4 sv = *(const int4*)(ei + e0);
        int4 dv = *(const int4*)(ei + E + e0);
        int4 es = *(const int4*)(eslot + e0);
        float4 f0 = *(const float4*)(ef + (size_t)e0 * 3);      // e0k0 e0k1 e0k2 e1k0
        float4 f1 = *(const float4*)(ef + (size_t)e0 * 3 + 4);  // e1k1 e1k2 e2k0 e2k1
        float4 f2 = *(const float4*)(ef + (size_t)e0 * 3 + 8);  // e2k2 e3k0 e3k1 e3k2
        float sa = s1[sv.x], sb = s1[sv.y], sc = s1[sv.z], sd = s1[sv.w];
        uint2 pa = PR[dv.x], pb = PR[dv.y], pc = PR[dv.z], pd = PR[dv.w];
        float s_a = sa + __uint_as_float(pa.x);
        float s_b = sb + __uint_as_float(pb.x);
        float s_c = sc + __uint_as_float(pc.x);
        float s_d = sd + __uint_as_float(pd.x);
        s_a = (s_a >= 0.f) ? s_a : ALPHA * s_a;
        s_b = (s_b >= 0.f) ? s_b : ALPHA * s_b;
        s_c = (s_c >= 0.f) ? s_c : ALPHA * s_c;
        s_d = (s_d >= 0.f) ? s_d : ALPHA * s_d;
        uint2 rv;
        rv.x = (uint32)sv.x | ((uint32)(f2bf(__expf(s_a * f0.x)) & 0x7fffu) << 17);
        rv.y = (uint32)(f2bf(__expf(s_a * f0.y)) & 0x7fffu)
             | ((uint32)(f2bf(__expf(s_a * f0.z)) & 0x7fffu) << 15);
        rec8[(int)pa.y + es.x] = rv;
        rv.x = (uint32)sv.y | ((uint32)(f2bf(__expf(s_b * f0.w)) & 0x7fffu) << 17);
        rv.y = (uint32)(f2bf(__expf(s_b * f1.x)) & 0x7fffu)
             | ((uint32)(f2bf(__expf(s_b * f1.y)) & 0x7fffu) << 15);
        rec8[(int)pb.y + es.y] = rv;
        rv.x = (uint32)sv.z | ((uint32)(f2bf(__expf(s_c * f1.z)) & 0x7fffu) << 17);
        rv.y = (uint32)(f2bf(__expf(s_c * f1.w)) & 0x7fffu)
             | ((uint32)(f2bf(__expf(s_c * f2.x)) & 0x7fffu) << 15);
        rec8[(int)pc.y + es.z] = rv;
        rv.x = (uint32)sv.w | ((uint32)(f2bf(__expf(s_d * f2.y)) & 0x7fffu) << 17);
        rv.y = (uint32)(f2bf(__expf(s_d * f2.z)) & 0x7fffu)
             | ((uint32)(f2bf(__expf(s_d * f2.w)) & 0x7fffu) << 15);
        rec8[(int)pd.y + es.w] = rv;
    } else {
        for (int e = e0; e < E; ++e) {
            int src = ei[e];
            int dst = ei[E + e];
            uint2 pr = PR[dst];
            float s = s1[src] + __uint_as_float(pr.x);
            s = (s >= 0.f) ? s : ALPHA * s;
            unsigned short b0 = f2bf(__expf(s * ef[(size_t)e * 3 + 0]));
            unsigned short b1 = f2bf(__expf(s * ef[(size_t)e * 3 + 1]));
            unsigned short b2 = f2bf(__expf(s * ef[(size_t)e * 3 + 2]));
            uint2 rv;
            rv.x = (uint32)src | ((uint32)(b0 & 0x7fffu) << 17);
            rv.y = (uint32)(b1 & 0x7fffu) | ((uint32)(b2 & 0x7fffu) << 15);
            rec8[(int)pr.y + eslot[e]] = rv;
        }
    }
}

// ---------------------------------------------------------------------------
// agg: one wave per node, atomic-free, one pass, SCALARIZED + software-
// pipelined: the NEXT x8 batch's rec8 records (SGPR s_loads) are issued
// while the current batch's Yu gathers are in flight — hides the ~200cy
// rec8 latency. Weight decode on SALU; FMAs take SGPR weight directly.
// [r3/r6 lessons: no cursor atomics, no LDS flush, no inter-wave barrier]
// ---------------------------------------------------------------------------
__global__ __launch_bounds__(256) void agg_kernel(const uint2* __restrict__ rec8,
                                                  const int* __restrict__ rowptr,
                                                  const uint32* __restrict__ Yu,
                                                  uint32* __restrict__ zo, int N) {
    int node = (blockIdx.x * blockDim.x + threadIdx.x) >> 6;
    int lane = threadIdx.x & 63;
    if (node >= N) return;
    int nu  = __builtin_amdgcn_readfirstlane(node);
    int beg = rowptr[nu], end = rowptr[nu + 1];

    float d0 = 0.f, d1 = 0.f, d2 = 0.f;
    float z0l = 0.f, z0h = 0.f, z1l = 0.f, z1h = 0.f, z2l = 0.f, z2h = 0.f;
    int j = beg;

    uint2 rr[8];
    if (j + 7 < end) {
        const uint2* rb = rec8 + (unsigned)__builtin_amdgcn_readfirstlane(j);
#pragma unroll
        for (int q = 0; q < 8; ++q) rr[q] = rb[q];
    }
    while (j + 7 < end) {
        uint32 sx[8], sy[8];
#pragma unroll
        for (int q = 0; q < 8; ++q) {
            sx[q] = __builtin_amdgcn_readfirstlane(rr[q].x);
            sy[q] = __builtin_amdgcn_readfirstlane(rr[q].y);
        }
        uint32 u[8];
#pragma unroll
        for (int q = 0; q < 8; ++q)
            u[q] = Yu[(size_t)(sx[q] & 0x1ffffu) * 64 + lane];
        int jn = j + 8;
        if (jn + 7 < end) {                       // prefetch next batch (SGPR)
            const uint2* rb = rec8 + (unsigned)__builtin_amdgcn_readfirstlane(jn);
#pragma unroll
            for (int q = 0; q < 8; ++q) rr[q] = rb[q];
        }
#pragma unroll
        for (int q = 0; q < 8; ++q) {
            float w0 = __uint_as_float((sx[q] >> 1) & 0x7fff0000u);
            float w1 = __uint_as_float((sy[q] << 16) & 0x7fff0000u);
            float w2 = __uint_as_float((sy[q] << 1) & 0x7fff0000u);
            d0 += w0; d1 += w1; d2 += w2;
            float yl = bflo(u[q]), yh = bfhi(u[q]);
            z0l += w0 * yl; z0h += w0 * yh;
            z1l += w1 * yl; z1h += w1 * yh;
            z2l += w2 * yl; z2h += w2 * yh;
        }
        j = jn;
    }
    for (; j + 3 < end; j += 4) {
        const uint2* rb = rec8 + (unsigned)__builtin_amdgcn_readfirstlane(j);
        uint2 r4[4];
#pragma unroll
        for (int q = 0; q < 4; ++q) r4[q] = rb[q];
        uint32 sx[4], sy[4];
#pragma unroll
        for (int q = 0; q < 4; ++q) {
            sx[q] = __builtin_amdgcn_readfirstlane(r4[q].x);
            sy[q] = __builtin_amdgcn_readfirstlane(r4[q].y);
        }
        uint32 u[4];
#pragma unroll
        for (int q = 0; q < 4; ++q)
            u[q] = Yu[(size_t)(sx[q] & 0x1ffffu) * 64 + lane];
#pragma unroll
        for (int q = 0; q < 4; ++q) {
            float w0 = __uint_as_float((sx[q] >> 1) & 0x7fff0000u);
            float w1 = __uint_as_float((sy[q] << 16) & 0x7fff0000u);
            float w2 = __uint_as_float((sy[q] << 1) & 0x7fff0000u);
            d0 += w0; d1 += w1; d2 += w2;
            float yl = bflo(u[q]), yh = bfhi(u[q]);
            z0l += w0 * yl; z0h += w0 * yh;
            z1l += w1 * yl; z1h += w1 * yh;
            z2l += w2 * yl; z2h += w2 * yh;
        }
    }
    for (; j < end; ++j) {
        const uint2* rb = rec8 + (unsigned)__builtin_amdgcn_readfirstlane(j);
        uint2 r0 = rb[0];
        uint32 sx = __builtin_amdgcn_readfirstlane(r0.x);
        uint32 sy = __builtin_amdgcn_readfirstlane(r0.y);
        uint32 u0 = Yu[(size_t)(sx & 0x1ffffu) * 64 + lane];
        float w0 = __uint_as_float((sx >> 1) & 0x7fff0000u);
        float w1 = __uint_as_float((sy << 16) & 0x7fff0000u);
        float w2 = __uint_as_float((sy << 1) & 0x7fff0000u);
        d0 += w0; d1 += w1; d2 += w2;
        float yl = bflo(u0), yh = bfhi(u0);
        z0l += w0 * yl; z0h += w0 * yh;
        z1l += w1 * yl; z1h += w1 * yh;
        z2l += w2 * yl; z2h += w2 * yh;
    }
    float i0 = 1.f / (d0 + 1e-16f);
    float i1 = 1.f / (d1 + 1e-16f);
    float i2 = 1.f / (d2 + 1e-16f);
    size_t zb = (size_t)node * 192;
    zo[zb + lane]       = pk2bf(z0l * i0, z0h * i0);
    zo[zb + 64 + lane]  = pk2bf(z1l * i1, z1h * i1);
    zo[zb + 128 + lane] = pk2bf(z2l * i2, z2h * i2);
}

// ---------------------------------------------------------------------------
// K5: out[N,128] = z[N,384] @ Wout[384,128].   [round-2 verbatim]
// z is L2-warm (agg just wrote it); fusion attempts (r3/r4/r6) all cost more
// than the round-trip saves.
// ---------------------------------------------------------------------------
__global__ __launch_bounds__(256) void k5_gemm(const unsigned short* __restrict__ z,
                                               const unsigned short* __restrict__ WoutT,
                                               float* __restrict__ out, int M) {
    __shared__ __align__(16) char smem[49152];
    unsigned short* As = (unsigned short*)smem;            // 64*128 bf16 = 16KB
    unsigned short* Bs = (unsigned short*)(smem + 16384);  // 128*128 bf16 = 32KB
    float* Ct = (float*)smem;                              // 64*132 f32 (epilogue)
    const int tid = threadIdx.x;
    const int lane = tid & 63, w = tid >> 6;
    const int ml = lane & 15, quad = lane >> 4;
    const int row0 = blockIdx.x * 64;

    f32x4 acc[8];
#pragma unroll
    for (int nt = 0; nt < 8; ++nt) acc[nt] = (f32x4){0.f, 0.f, 0.f, 0.f};

    for (int ks = 0; ks < 3; ++ks) {
        __syncthreads();              // prev slice compute done
#pragma unroll
        for (int m = 0; m < 4; ++m) { // stage A slice: 64 rows x 128 bf16
            int i = m * 256 + tid;
            int r = i >> 4, g = i & 15;
            int rg = row0 + r;
            uint4 v = make_uint4(0u, 0u, 0u, 0u);
            if (rg < M) v = *(const uint4*)(z + (size_t)rg * 384 + ks * 128 + g * 8);
            *(uint4*)(As + r * 128 + ((g ^ (r & 15)) * 8)) = v;
        }
#pragma unroll
        for (int m = 0; m < 8; ++m) { // stage B slice: 128 n-rows x 128 k
            int i = m * 256 + tid;
            int n = i >> 4, g = i & 15;
            uint4 v = *(const uint4*)(WoutT + n * 384 + ks * 128 + g * 8);
            *(uint4*)(Bs + n * 128 + ((g ^ (n & 15)) * 8)) = v;
        }
        __syncthreads();
#pragma unroll
        for (int kc = 0; kc < 4; ++kc) {
            int gl = ((kc * 4 + quad) ^ ml) * 8;
            short8 af = *(const short8*)(As + (w * 16 + ml) * 128 + gl);
#pragma unroll
            for (int nt = 0; nt < 8; ++nt) {
                short8 bf = *(const short8*)(Bs + (nt * 16 + ml) * 128 + gl);
                acc[nt] = __builtin_amdgcn_mfma_f32_16x16x32_bf16(af, bf, acc[nt], 0, 0, 0);
            }
        }
    }
    __syncthreads();
    int lrow = w * 16 + quad * 4;
#pragma unroll
    for (int r = 0; r < 4; ++r)
#pragma unroll
        for (int nt = 0; nt < 8; ++nt)
            Ct[(lrow + r) * 132 + nt * 16 + ml] = acc[nt][r];
    __syncthreads();
#pragma unroll
    for (int m = 0; m < 8; ++m) {
        int i = m * 256 + tid;
        int r2 = i >> 5, g = i & 31;
        int rg = row0 + r2;
        if (rg < M)
            *(float4*)(out + (size_t)rg * 128 + g * 4) = *(const float4*)(Ct + r2 * 132 + g * 4);
    }
}

// ---------------------------------------------------------------------------
extern "C" void kernel_launch(void* const* d_in, const int* in_sizes, int n_in,
                              void* d_out, int out_size, void* d_ws, size_t ws_size,
                              hipStream_t stream) {
    const float* h    = (const float*)d_in[0];
    const int*   ei   = (const int*)d_in[1];    // [2, E]
    const float* ef   = (const float*)d_in[2];  // [E, 3]
    const float* W    = (const float*)d_in[3];  // [128,128]
    const float* a1   = (const float*)d_in[4];  // [128]
    const float* a2   = (const float*)d_in[5];  // [128]
    const float* Wout = (const float*)d_in[6];  // [384,128]
    float*       out  = (float*)d_out;

    const int N = in_sizes[0] / 128;  // 50000
    const int E = in_sizes[2] / 3;    // 800000
    const int nchunk = (N + 1023) / 1024;
    const int nbh    = (E + 1023) / 1024;  // hist blocks (4 edges/thread)
    const int nbm    = (N + 63) / 64;      // mmy blocks

    // workspace layout (rec8 first -> 16B alignment for everything vectorized)
    uint2* rec8 = (uint2*)d_ws;                           // E * 8B
    unsigned short* Whb = (unsigned short*)(rec8 + E);    // N*128 bf16 (12.8MB)
    unsigned short* WBT = Whb + (size_t)N * 128;          // 128*128 bf16
    unsigned short* WoutT = WBT + 128 * 128;              // 128*384 bf16
    float* w1f  = (float*)(WoutT + 128 * 384);            // 128
    float* w2f  = w1f + 128;                              // 128
    float* s1   = w2f + 128;                              // N
    uint2* PR   = (uint2*)(s1 + N);                       // N pairs {s2, rowptr}
    int* rowptr = (int*)(PR + N);                         // N+4 (16B-align pad)
    unsigned short* zbuf = (unsigned short*)(rowptr + N + 4);  // N*384 bf16 (38.4MB)
    // counts/eslot alias zbuf: dead before agg writes z (stream order)
    int* counts = (int*)zbuf;                             // N
    int* eslot  = counts + N;                             // E

    (void)hipMemsetAsync(counts, 0, (size_t)N * sizeof(int), stream);

    k1_hist_prep<<<nbh + 25, 256, 0, stream>>>(ei, counts, eslot, E,
                                               W, Wout, a1, a2, WBT, WoutT, w1f, w2f, nbh);
    k2_mmy_scan<<<nbm + nchunk, 256, 0, stream>>>(h, WBT, w1f, w2f, Whb, s1, PR, N,
                                                  counts, rowptr, N, E, nbm);
    scatter_kernel<<<(E / 4 + 255) / 256, 256, 0, stream>>>(ei, ef, s1, PR, eslot, rec8, E);
    agg_kernel<<<(N * 64 + 255) / 256, 256, 0, stream>>>(rec8, rowptr, (const uint32*)Whb,
                                                         (uint32*)zbuf, N);
    k5_gemm<<<(N + 63) / 64, 256, 0, stream>>>(zbuf, WoutT, out, N);
}